// Round 1
// baseline (208.822 us; speedup 1.0000x reference)
//
#include <hip/hip_runtime.h>

#define NPF 16
#define NH 8
#define NV 16
#define NN 900
#define ND 256
#define NB 4

__global__ __launch_bounds__(256) void hough_fused(
    const float* __restrict__ queries,
    const float* __restrict__ cur_ref,
    const float* __restrict__ vote_w,
    const float* __restrict__ vote_b,
    const float* __restrict__ proj_w,
    const float* __restrict__ proj_b,
    float* __restrict__ out)
{
    __shared__ __align__(16) float qs[ND];     // staged query row
    __shared__ float part[256];                // vote partials
    __shared__ float vp[NV * 2];               // vote positions (x,y)*16
    __shared__ float s2i[NV];                  // 0.5/sigma^2 per v
    __shared__ float row[NN];                  // imap row (pre-normalization)
    __shared__ float red[4];
    __shared__ float s_inv;

    const int tid = threadIdx.x;
    const int bn  = blockIdx.x;
    const int b   = bn / NN;
    const int n   = bn - b * NN;

    // ---- stage query row ----
    qs[tid] = queries[(size_t)bn * ND + tid];
    __syncthreads();

    // ---- votes: 32 outputs, 8 threads each over D=256 ----
    {
        const int o     = tid & 31;
        const int chunk = tid >> 5;
        const float4* wv = (const float4*)(vote_w + o * ND + chunk * 32);
        const float4* qv = (const float4*)(qs + chunk * 32);
        float p = 0.f;
#pragma unroll
        for (int j = 0; j < 8; j++) {
            float4 w4 = wv[j];
            float4 q4 = qv[j];
            p += w4.x * q4.x + w4.y * q4.y + w4.z * q4.z + w4.w * q4.w;
        }
        part[tid] = p;
    }
    __syncthreads();

    if (tid < 32) {
        float s = vote_b[tid];
#pragma unroll
        for (int c = 0; c < 8; c++) s += part[c * 32 + tid];
        // vote_pos[v][c] = cur_ref[b,n,c] + votes,  o = 2v+c
        vp[tid] = s + cur_ref[((size_t)b * NN + n) * 4 + (tid & 1)];
    } else if (tid >= 64 && tid < 64 + NV) {
        // sigma index quirk: sigma_flat[b, i] = sigma[b, i % N], i = n*V + v
        int v = tid - 64;
        int j = (n * NV + v) % NN;
        float c2 = cur_ref[((size_t)b * NN + j) * 4 + 2];
        float c3 = cur_ref[((size_t)b * NN + j) * 4 + 3];
        float sg = (c2 + c3) * 0.25f;       // mean(c2,c3)/2
        s2i[v] = 0.5f / (sg * sg);          // 1/(2*sigma^2)
    }
    __syncthreads();

    // ---- hoist per-row vote data into registers ----
    float px[NV], py[NV], pp[NV], s2v[NV];
#pragma unroll
    for (int v = 0; v < NV; v++) {
        px[v]  = vp[2 * v];
        py[v]  = vp[2 * v + 1];
        pp[v]  = px[v] * px[v] + py[v] * py[v];   // sum(vf^2) like reference
        s2v[v] = s2i[v];
    }

    // ---- imap row: 51.8M exp total across grid ----
    float lsum = 0.f;
    for (int m = tid; m < NN; m += 256) {
        float4 cr = ((const float4*)cur_ref)[(size_t)b * NN + m];
        float cx = cr.x, cy = cr.y;
        float cc = cx * cx + cy * cy;
        float acc = 0.f;
#pragma unroll
        for (int v = 0; v < NV; v++) {
            float d2 = pp[v] + cc - 2.f * (px[v] * cx + py[v] * cy);
            d2 = fmaxf(d2, 0.f);
            acc += __expf(-d2 * s2v[v]);
        }
        row[m] = acc;
        lsum += fabsf(acc);
    }

    // ---- block reduce row sum ----
#pragma unroll
    for (int off = 32; off > 0; off >>= 1) lsum += __shfl_down(lsum, off, 64);
    if ((tid & 63) == 0) red[tid >> 6] = lsum;
    __syncthreads();
    if (tid == 0) {
        float s = red[0] + red[1] + red[2] + red[3];
        s_inv = 1.0f / fmaxf(s, 1e-12f);
    }
    __syncthreads();
    const float inv = s_inv;

    // ---- epilogue: sine embed + projection + relu ----
    // preload all 128 proj weights + 8 biases into registers (once per thread)
    float W[NH * NPF];
#pragma unroll
    for (int i = 0; i < NH * NPF; i++) W[i] = proj_w[i];
    float Pb[NH];
#pragma unroll
    for (int h = 0; h < NH; h++) Pb[h] = proj_b[h];

    // 100 / 10000^(k/8)
    const float invt[8] = {100.0f, 31.622776601683793f, 10.0f, 3.1622776601683795f,
                           1.0f, 0.31622776601683794f, 0.1f, 0.031622776601683791f};

    for (int m = tid; m < NN; m += 256) {
        float x = 1.0f - row[m] * inv;
        float sk[8], ck[8];
#pragma unroll
        for (int k = 0; k < 8; k++) {
            float a = x * invt[k];
            sk[k] = __sinf(a);
            ck[k] = __cosf(a);
        }
        size_t base = ((size_t)(b * NH) * NN + n) * NN + m;
#pragma unroll
        for (int h = 0; h < NH; h++) {
            float o = Pb[h];
#pragma unroll
            for (int k = 0; k < 8; k++) {
                o = fmaf(W[h * NPF + 2 * k],     sk[k], o);
                o = fmaf(W[h * NPF + 2 * k + 1], ck[k], o);
            }
            out[base + (size_t)h * NN * NN] = fmaxf(o, 0.f);
        }
    }
}

extern "C" void kernel_launch(void* const* d_in, const int* in_sizes, int n_in,
                              void* d_out, int out_size, void* d_ws, size_t ws_size,
                              hipStream_t stream) {
    const float* queries = (const float*)d_in[0];
    const float* cur_ref = (const float*)d_in[1];
    // d_in[2] = prev_ref_points: unused by the reference
    const float* vote_w  = (const float*)d_in[3];
    const float* vote_b  = (const float*)d_in[4];
    const float* proj_w  = (const float*)d_in[5];
    const float* proj_b  = (const float*)d_in[6];
    float* out = (float*)d_out;

    hough_fused<<<NB * NN, 256, 0, stream>>>(queries, cur_ref, vote_w, vote_b,
                                             proj_w, proj_b, out);
}